// Round 8
// baseline (290.205 us; speedup 1.0000x reference)
//
#include <hip/hip_runtime.h>

// SpatialTransformer: 3D trilinear warp with dense displacement field.
// vol: [B,D,H,W,C] f32, trf: [B,D,H,W,3] f32 -> out: [B,D,H,W,C] f32
// B=2, D=H=W=160, C=2 (fixed by setup_inputs).
//
// R13: vectorize the STREAMING requests (trf + store) via lane-owns-4-
// consecutive-voxels mapping.
// Model re-fit over R5..R12 (cycles/voxel/CU: 12.7, 8.0, 7.1-7.5 flat):
// the only currency tracking all rounds is PER-LANE VMEM requests/voxel
// (~1.3-1.7 cyc each through the TCP pipe, hit or miss):
//   R5 = 4 gather + 3 trf + 1 store = 8  -> 12.7
//   R8+ = 2 + 3 + 1 = 6                  -> 7.1-8.0
// R9/R12 cut distinct-line touches only -> flat (falsified line models).
// Fix: v = base + tid*4 + kk. Per lane: trf = 48 contiguous B = 3 dwordx4
// (0.75 req/voxel, was 3 scalar dwords); store = 32 contiguous B =
// 2 dwordx4 (0.5, was 1). Gathers unchanged (2/voxel). Total 6 -> 3.25.
// 160 % 4 == 0 and 3200 % 4 == 0 -> a lane's 4 voxels never straddle a
// w-row or d-plane (d,hh computed once; w = w0 + kk); all accesses 16B-
// aligned. Arithmetic per voxel IDENTICAL -> absmax exactly 0.25 again.
// Predict: main 95 -> 52-65us combined, total ~235-250us, VALUBusy -2-4pts.
// If flat: lane-request model falsified -> structural plateau (2 gather
// misses/voxel at TCP miss rate), declare roofline with that arithmetic.
//
// Retained: fp16 full-cell pack P16[p][8]={d0,d1}x{h0,h1}x{c0,c1} (clamp-
// baked, 16B/cell, 131MB ws), batch-split main (set 147MB < L3), 8 h-slice
// XCD regions, sched_barrier(0) fences (R11, +7us), w-boundary folded into
// weights (exact). Fallback tiers: ws>=131MB -> R13; >=65.5MB -> R8; else f32.

#define BLK 256
constexpr int Bn = 2, Dn = 160, Hn = 160, Wn = 160;
constexpr int HQ = 40;                    // h-quarter rows (fallback paths)
constexpr int RSTRIP = HQ * Wn;           // 6400 voxels per (d, quarter) plane
constexpr int HQ2 = 20;                   // h-slice rows per XCD region (split)
constexpr int RSTRIP2 = HQ2 * Wn;         // 3200 voxels per (d, slice) plane
constexpr int V = 4;                      // voxels per thread

typedef float    f32x2  __attribute__((ext_vector_type(2)));
typedef float    f32x4  __attribute__((ext_vector_type(4), aligned(8)));   // vol reads (8B-safe)
typedef float    f32x4a __attribute__((ext_vector_type(4), aligned(16)));  // trf/out: 16B-aligned
typedef _Float16 h16x8  __attribute__((ext_vector_type(8), aligned(8)));   // R8 chunk at byte 8p
typedef _Float16 h16x16 __attribute__((ext_vector_type(16), aligned(16))); // cell pair at byte 16p

// ================= repack: vol f32 -> P16[p][8] = 8 cell corners ===========
// P16[p] = {d0h0c0,d0h0c1,d0h1c0,d0h1c1,d1h0c0,d1h0c1,d1h1c0,d1h1c1},
// d1/h1 clamp-baked. Each thread packs 2 consecutive-w voxels.
__global__ __launch_bounds__(BLK) void repack_dh(
    const float* __restrict__ vol, _Float16* __restrict__ pk)
{
    const int t  = blockIdx.x * BLK + threadIdx.x;   // 0 .. nvox/2-1
    const int v0 = t * 2;                            // even voxel id
    const int w  = v0 % Wn;                          // even (Wn%2==0)
    const int r  = v0 / Wn;                          // row id = (b*Dn+d)*Hn+h
    const int h  = r % Hn;
    const int d  = (r / Hn) % Dn;
    const int dh = (h < Hn - 1) ? 1 : 0;             // h-step (clamped)
    const int dd = (d < Dn - 1) ? Hn : 0;            // d-step in rows (clamped)

    const int r00 = r;                               // (d ,h )
    const int r01 = r + dh;                          // (d ,h1)
    const int r10 = r + dd;                          // (d1,h )
    const int r11 = r + dd + dh;                     // (d1,h1)

    const f32x4 A = *(const f32x4*)(vol + ((long long)(r00 * Wn + w) << 1));
    const f32x4 B = *(const f32x4*)(vol + ((long long)(r01 * Wn + w) << 1));
    const f32x4 C = *(const f32x4*)(vol + ((long long)(r10 * Wn + w) << 1));
    const f32x4 D = *(const f32x4*)(vol + ((long long)(r11 * Wn + w) << 1));

    h16x16 o;
    // voxel v0 (w):    x=c0, y=c1
    o[0]  = (_Float16)A.x; o[1]  = (_Float16)A.y;    // d0h0
    o[2]  = (_Float16)B.x; o[3]  = (_Float16)B.y;    // d0h1
    o[4]  = (_Float16)C.x; o[5]  = (_Float16)C.y;    // d1h0
    o[6]  = (_Float16)D.x; o[7]  = (_Float16)D.y;    // d1h1
    // voxel v0+1 (w+1): z=c0, w=c1
    o[8]  = (_Float16)A.z; o[9]  = (_Float16)A.w;
    o[10] = (_Float16)B.z; o[11] = (_Float16)B.w;
    o[12] = (_Float16)C.z; o[13] = (_Float16)C.w;
    o[14] = (_Float16)D.z; o[15] = (_Float16)D.w;
    *(h16x16*)(pk + ((long long)v0 << 3)) = o;       // 32B at byte 16*v0
}

// ================= R13 main: lane-owns-4-voxels, one batch per dispatch ====
__global__ __launch_bounds__(BLK, 4) void st_warp_kernel_v4(
    const _Float16* __restrict__ pk,
    const float* __restrict__ trf,
    float* __restrict__ out,
    const int b)
{
    const int tid = threadIdx.x;
    const int sl  = blockIdx.x & 7;          // h-slice region (XCD heuristic)
    const int j   = blockIdx.x >> 3;         // 0..499 within region
    const int h0  = sl * HQ2;                // h-slice origin

    // ---- phase 0: lane base (4 consecutive voxels) + vectorized trf ----
    const int v0  = j * (BLK * V) + tid * V;         // region-linear base voxel
    const int d   = v0 / RSTRIP2;                    // same d for all 4 (3200%4==0)
    const int rem = v0 - d * RSTRIP2;
    const int hh  = rem / Wn;                        // same row for all 4 (160%4==0)
    const int w0  = rem - hh * Wn;                   // w0, w0+1, w0+2, w0+3
    const int h   = h0 + hh;
    const long long gbase = ((long long)(b * Dn + d) * Hn + h) * Wn + w0;

    // 48B of trf for this lane's 4 voxels: 3 x dwordx4 (16B-aligned)
    const float* tp = trf + gbase * 3;
    f32x4a t0, t1, t2;
    t0 = __builtin_nontemporal_load((const f32x4a*)(tp + 0));
    t1 = __builtin_nontemporal_load((const f32x4a*)(tp + 4));
    t2 = __builtin_nontemporal_load((const f32x4a*)(tp + 8));
    __builtin_amdgcn_sched_barrier(0);   // keep the 3 trf loads issued here

    // per-voxel displacement components (compile-time unpack)
    float sd[V], sh[V], sw[V];
    sd[0] = t0[0]; sh[0] = t0[1]; sw[0] = t0[2];
    sd[1] = t0[3]; sh[1] = t1[0]; sw[1] = t1[1];
    sd[2] = t1[2]; sh[2] = t1[3]; sw[2] = t2[0];
    sd[3] = t2[1]; sh[3] = t2[2]; sw[3] = t2[3];

    // ---- phase 1: weights + issue ALL V 32B cell gathers ----
    h16x16 val[V];
    float wA[V], wB[V], wC[V], wD[V], w0k[V], w1k[V];
    #pragma unroll
    for (int k = 0; k < V; ++k) {
        float loc, c0f, c1f;

        loc = (float)d + sd[k];
        c0f = fminf(fmaxf(floorf(loc), 0.0f), (float)(Dn - 1));
        c1f = fminf(c0f + 1.0f, (float)(Dn - 1));
        const float wd0 = c1f - loc, wd1 = 1.0f - wd0;
        const int id0 = (int)c0f;                 // id1 baked into packed data

        loc = (float)h + sh[k];
        c0f = fminf(fmaxf(floorf(loc), 0.0f), (float)(Hn - 1));
        c1f = fminf(c0f + 1.0f, (float)(Hn - 1));
        const float wh0 = c1f - loc, wh1 = 1.0f - wh0;
        const int ih0 = (int)c0f;                 // ih1 baked into packed data

        loc = (float)(w0 + k) + sw[k];
        c0f = fminf(fmaxf(floorf(loc), 0.0f), (float)(Wn - 1));
        c1f = fminf(c0f + 1.0f, (float)(Wn - 1));
        const float ww0 = c1f - loc, ww1 = 1.0f - ww0;
        const int iw0 = (int)c0f;

        const bool lo = (iw0 < Wn - 1);
        const int  m  = lo ? iw0 : (Wn - 2);
        // boundary: corner0 weight -> 0, corner1 weight -> 1 (exact: ww0+ww1==1)
        w0k[k] = lo ? ww0 : 0.0f;
        w1k[k] = lo ? ww1 : 1.0f;
        wA[k] = wd0 * wh0; wB[k] = wd0 * wh1;
        wC[k] = wd1 * wh0; wD[k] = wd1 * wh1;

        const long long p0 = ((b * Dn + id0) * Hn + ih0) * Wn + m;  // w-pair base
        val[k] = *(const h16x16*)(pk + (p0 << 3));   // 32B: cells p0, p0+1
    }
    __builtin_amdgcn_sched_barrier(0);   // keep all 8 cell loads issued here

    // ---- phase 2: convert + combine + vectorized store (2 x dwordx4) ----
    float acc0[V], acc1[V];
    #pragma unroll
    for (int k = 0; k < V; ++k) {
        const h16x16 v = val[k];
        // layout: [i] w-corner0, [8+i] w-corner1; i = d*4 + h*2 + c
        acc0[k] =
              wA[k] * (w0k[k] * (float)v[0] + w1k[k] * (float)v[8])
            + wB[k] * (w0k[k] * (float)v[2] + w1k[k] * (float)v[10])
            + wC[k] * (w0k[k] * (float)v[4] + w1k[k] * (float)v[12])
            + wD[k] * (w0k[k] * (float)v[6] + w1k[k] * (float)v[14]);
        acc1[k] =
              wA[k] * (w0k[k] * (float)v[1] + w1k[k] * (float)v[9])
            + wB[k] * (w0k[k] * (float)v[3] + w1k[k] * (float)v[11])
            + wC[k] * (w0k[k] * (float)v[5] + w1k[k] * (float)v[13])
            + wD[k] * (w0k[k] * (float)v[7] + w1k[k] * (float)v[15]);
    }
    float* op = out + gbase * 2;                     // 32B, 16B-aligned
    f32x4a r0, r1;
    r0[0] = acc0[0]; r0[1] = acc1[0]; r0[2] = acc0[1]; r0[3] = acc1[1];
    r1[0] = acc0[2]; r1[1] = acc1[2]; r1[2] = acc0[3]; r1[3] = acc1[3];
    __builtin_nontemporal_store(r0, (f32x4a*)(op + 0));
    __builtin_nontemporal_store(r1, (f32x4a*)(op + 4));
}

// ================= R8 tier: h-pair pack (known-good middle fallback) =======
__global__ __launch_bounds__(BLK) void repack_h_pairs(
    const float* __restrict__ vol, _Float16* __restrict__ pk)
{
    const int t  = blockIdx.x * BLK + threadIdx.x;   // 0 .. 4,095,999
    const int v0 = t * 2;                            // even voxel id
    const int w  = v0 % Wn;                          // even (Wn%2==0)
    const int r  = v0 / Wn;                          // row id = (b*Dn+d)*Hn+h
    const int h  = r % Hn;
    const int hc = (h < Hn - 1) ? (h + 1) : h;       // clamped h+1
    const int r1 = r - h + hc;                       // row id at hc

    const f32x4 a = *(const f32x4*)(vol + ((long long)v0 << 1));
    const f32x4 b = *(const f32x4*)(vol + ((long long)(r1 * Wn + w) << 1));

    h16x8 o;
    o[0] = (_Float16)a.x; o[1] = (_Float16)a.y;
    o[2] = (_Float16)b.x; o[3] = (_Float16)b.y;
    o[4] = (_Float16)a.z; o[5] = (_Float16)a.w;
    o[6] = (_Float16)b.z; o[7] = (_Float16)b.w;
    *(h16x8*)(pk + ((long long)v0 << 2)) = o;
}

__global__ __launch_bounds__(BLK, 4) void st_warp_kernel_pk(
    const _Float16* __restrict__ pk,
    const float* __restrict__ trf,
    float* __restrict__ out)
{
    const int tid = threadIdx.x;
    const int xcd = blockIdx.x & 7;
    const int j   = blockIdx.x >> 3;
    const int b   = xcd >> 2;
    const int h0  = (xcd & 3) * HQ;

    int   gvox[V];
    float sd[V], sh[V], sw[V];
    #pragma unroll
    for (int k = 0; k < V; ++k) {
        const int v   = j * (BLK * V) + k * BLK + tid;
        const int d   = v / RSTRIP;
        const int rem = v - d * RSTRIP;
        const int hh  = rem / Wn;
        const int w   = rem - hh * Wn;
        gvox[k] = ((b * Dn + d) * Hn + (h0 + hh)) * Wn + w;
    }
    #pragma unroll
    for (int k = 0; k < V; ++k) {
        const float* tp = trf + (long long)gvox[k] * 3;
        sd[k] = __builtin_nontemporal_load(tp + 0);
        sh[k] = __builtin_nontemporal_load(tp + 1);
        sw[k] = __builtin_nontemporal_load(tp + 2);
    }

    h16x8 val[2 * V];
    float wA[V], wB[V], wC[V], wD[V], w0[V], w1[V];
    #pragma unroll
    for (int k = 0; k < V; ++k) {
        const int v   = j * (BLK * V) + k * BLK + tid;
        const int d   = v / RSTRIP;
        const int rem = v - d * RSTRIP;
        const int hh  = rem / Wn;
        const int w   = rem - hh * Wn;
        const int h   = h0 + hh;

        float loc, c0f, c1f;

        loc = (float)d + sd[k];
        c0f = fminf(fmaxf(floorf(loc), 0.0f), (float)(Dn - 1));
        c1f = fminf(c0f + 1.0f, (float)(Dn - 1));
        const float wd0 = c1f - loc, wd1 = 1.0f - wd0;
        const int id0 = (int)c0f, id1 = (int)c1f;

        loc = (float)h + sh[k];
        c0f = fminf(fmaxf(floorf(loc), 0.0f), (float)(Hn - 1));
        c1f = fminf(c0f + 1.0f, (float)(Hn - 1));
        const float wh0 = c1f - loc, wh1 = 1.0f - wh0;
        const int ih0 = (int)c0f;

        loc = (float)w + sw[k];
        c0f = fminf(fmaxf(floorf(loc), 0.0f), (float)(Wn - 1));
        c1f = fminf(c0f + 1.0f, (float)(Wn - 1));
        const float ww0 = c1f - loc, ww1 = 1.0f - ww0;
        const int iw0 = (int)c0f;

        const bool lo = (iw0 < Wn - 1);
        const int  m  = lo ? iw0 : (Wn - 2);
        w0[k] = lo ? ww0 : 0.0f;
        w1[k] = lo ? ww1 : 1.0f;
        wA[k] = wd0 * wh0; wB[k] = wd0 * wh1;
        wC[k] = wd1 * wh0; wD[k] = wd1 * wh1;

        const int bo = b * Dn;
        const int p0 = ((bo + id0) * Hn + ih0) * Wn + m;
        const int p1 = ((bo + id1) * Hn + ih0) * Wn + m;

        val[2 * k + 0] = *(const h16x8*)(pk + ((long long)p0 << 2));
        val[2 * k + 1] = *(const h16x8*)(pk + ((long long)p1 << 2));
    }

    #pragma unroll
    for (int k = 0; k < V; ++k) {
        const h16x8 a = val[2 * k + 0];
        const h16x8 c = val[2 * k + 1];
        const float acc0 =
              wA[k] * (w0[k] * (float)a[0] + w1[k] * (float)a[4])
            + wB[k] * (w0[k] * (float)a[2] + w1[k] * (float)a[6])
            + wC[k] * (w0[k] * (float)c[0] + w1[k] * (float)c[4])
            + wD[k] * (w0[k] * (float)c[2] + w1[k] * (float)c[6]);
        const float acc1 =
              wA[k] * (w0[k] * (float)a[1] + w1[k] * (float)a[5])
            + wB[k] * (w0[k] * (float)a[3] + w1[k] * (float)a[7])
            + wC[k] * (w0[k] * (float)c[1] + w1[k] * (float)c[5])
            + wD[k] * (w0[k] * (float)c[3] + w1[k] * (float)c[7]);
        f32x2 res; res.x = acc0; res.y = acc1;
        __builtin_nontemporal_store(res, &((f32x2*)out)[gvox[k]]);
    }
}

// ================= R5 tier: f32 direct (last-resort fallback) ==============
__global__ __launch_bounds__(BLK, 4) void st_warp_kernel_f32(
    const float* __restrict__ vol,
    const float* __restrict__ trf,
    float* __restrict__ out)
{
    const int tid = threadIdx.x;
    const int xcd = blockIdx.x & 7;
    const int j   = blockIdx.x >> 3;
    const int b   = xcd >> 2;
    const int h0  = (xcd & 3) * HQ;

    int   gvox[V];
    float sd[V], sh[V], sw[V];
    #pragma unroll
    for (int k = 0; k < V; ++k) {
        const int v   = j * (BLK * V) + k * BLK + tid;
        const int d   = v / RSTRIP;
        const int rem = v - d * RSTRIP;
        const int hh  = rem / Wn;
        const int w   = rem - hh * Wn;
        gvox[k] = ((b * Dn + d) * Hn + (h0 + hh)) * Wn + w;
    }
    #pragma unroll
    for (int k = 0; k < V; ++k) {
        const float* tp = trf + (long long)gvox[k] * 3;
        sd[k] = __builtin_nontemporal_load(tp + 0);
        sh[k] = __builtin_nontemporal_load(tp + 1);
        sw[k] = __builtin_nontemporal_load(tp + 2);
    }

    f32x4 val[4 * V];
    float wA[V], wB[V], wC[V], wD[V], w0[V], w1[V];
    #pragma unroll
    for (int k = 0; k < V; ++k) {
        const int v   = j * (BLK * V) + k * BLK + tid;
        const int d   = v / RSTRIP;
        const int rem = v - d * RSTRIP;
        const int hh  = rem / Wn;
        const int w   = rem - hh * Wn;
        const int h   = h0 + hh;

        float loc, c0f, c1f;

        loc = (float)d + sd[k];
        c0f = fminf(fmaxf(floorf(loc), 0.0f), (float)(Dn - 1));
        c1f = fminf(c0f + 1.0f, (float)(Dn - 1));
        const float wd0 = c1f - loc, wd1 = 1.0f - wd0;
        const int id0 = (int)c0f, id1 = (int)c1f;

        loc = (float)h + sh[k];
        c0f = fminf(fmaxf(floorf(loc), 0.0f), (float)(Hn - 1));
        c1f = fminf(c0f + 1.0f, (float)(Hn - 1));
        const float wh0 = c1f - loc, wh1 = 1.0f - wh0;
        const int ih0 = (int)c0f, ih1 = (int)c1f;

        loc = (float)w + sw[k];
        c0f = fminf(fmaxf(floorf(loc), 0.0f), (float)(Wn - 1));
        c1f = fminf(c0f + 1.0f, (float)(Wn - 1));
        const float ww0 = c1f - loc, ww1 = 1.0f - ww0;
        const int iw0 = (int)c0f;

        const bool lo = (iw0 < Wn - 1);
        const int  m  = lo ? iw0 : (Wn - 2);
        w0[k] = lo ? ww0 : 0.0f;
        w1[k] = lo ? ww1 : 1.0f;
        wA[k] = wd0 * wh0; wB[k] = wd0 * wh1;
        wC[k] = wd1 * wh0; wD[k] = wd1 * wh1;

        const int bo  = b * Dn;
        const int r00 = ((bo + id0) * Hn + ih0) * Wn;
        const int r01 = ((bo + id0) * Hn + ih1) * Wn;
        const int r10 = ((bo + id1) * Hn + ih0) * Wn;
        const int r11 = ((bo + id1) * Hn + ih1) * Wn;

        val[4 * k + 0] = *(const f32x4*)(vol + (((long long)(r00 + m)) << 1));
        val[4 * k + 1] = *(const f32x4*)(vol + (((long long)(r01 + m)) << 1));
        val[4 * k + 2] = *(const f32x4*)(vol + (((long long)(r10 + m)) << 1));
        val[4 * k + 3] = *(const f32x4*)(vol + (((long long)(r11 + m)) << 1));
    }

    #pragma unroll
    for (int k = 0; k < V; ++k) {
        const f32x4 vA = val[4 * k + 0], vB = val[4 * k + 1];
        const f32x4 vC = val[4 * k + 2], vD = val[4 * k + 3];
        const float acc0 = wA[k] * (w0[k] * vA.x + w1[k] * vA.z)
                         + wB[k] * (w0[k] * vB.x + w1[k] * vB.z)
                         + wC[k] * (w0[k] * vC.x + w1[k] * vC.z)
                         + wD[k] * (w0[k] * vD.x + w1[k] * vD.z);
        const float acc1 = wA[k] * (w0[k] * vA.y + w1[k] * vA.w)
                         + wB[k] * (w0[k] * vB.y + w1[k] * vB.w)
                         + wC[k] * (w0[k] * vC.y + w1[k] * vC.w)
                         + wD[k] * (w0[k] * vD.y + w1[k] * vD.w);
        f32x2 res; res.x = acc0; res.y = acc1;
        __builtin_nontemporal_store(res, &((f32x2*)out)[gvox[k]]);
    }
}

extern "C" void kernel_launch(void* const* d_in, const int* in_sizes, int n_in,
                              void* d_out, int out_size, void* d_ws, size_t ws_size,
                              hipStream_t stream) {
    const float* vol = (const float*)d_in[0];
    const float* trf = (const float*)d_in[1];
    float* out = (float*)d_out;

    const int nvox = Bn * Dn * Hn * Wn;               // 8,192,000
    const size_t pk16_bytes = (size_t)nvox * 8 * sizeof(_Float16);  // 131,072,000
    const size_t pk8_bytes  = (size_t)nvox * 4 * sizeof(_Float16);  //  65,536,000
    const int rgrid = (nvox / 2) / BLK;               // 16000 blocks

    if (d_ws != nullptr && ws_size >= pk16_bytes) {
        _Float16* pk = (_Float16*)d_ws;
        const int hgrid = (nvox / 2) / (BLK * V);     // 4000 blocks/batch, %8==0
        repack_dh<<<rgrid, BLK, 0, stream>>>(vol, pk);
        st_warp_kernel_v4<<<hgrid, BLK, 0, stream>>>(pk, trf, out, 0);
        st_warp_kernel_v4<<<hgrid, BLK, 0, stream>>>(pk, trf, out, 1);
    } else if (d_ws != nullptr && ws_size >= pk8_bytes) {
        _Float16* pk = (_Float16*)d_ws;
        const int grid = nvox / (BLK * V);            // 8000 blocks
        repack_h_pairs<<<rgrid, BLK, 0, stream>>>(vol, pk);
        st_warp_kernel_pk<<<grid, BLK, 0, stream>>>(pk, trf, out);
    } else {
        const int grid = nvox / (BLK * V);
        st_warp_kernel_f32<<<grid, BLK, 0, stream>>>(vol, trf, out);
    }
}

// Round 10
// 273.662 us; speedup vs baseline: 1.0605x; 1.0605x over previous
//
#include <hip/hip_runtime.h>

// SpatialTransformer: 3D trilinear warp with dense displacement field.
// vol: [B,D,H,W,C] f32, trf: [B,D,H,W,3] f32 -> out: [B,D,H,W,C] f32
// B=2, D=H=W=160, C=2 (fixed by setup_inputs).
//
// R15 = R14 with the asm hazard fixed. R14 NaN'd: separate asm blocks per
// load + separate waitcnt block let the compiler insert register-shuffling
// v_movs BETWEEN load-issue and waitcnt (it models asm outputs as defined
// synchronously) -> copies of undefined registers (r282-class hazard).
// Fix: ONE asm volatile block = 8x global_load_dwordx4 + s_waitcnt vmcnt(0),
// 8 early-clobber "=&v" outputs, 4 pointer inputs. Outputs are defined only
// at block end (after the hardware wait) -> no garbage-copy window; the
// consumer is ordered by true data dependence. Early-clobber prevents
// output/address overlap while 8 loads are in flight. Intent preserved:
// MLP 2 -> 8 per wave.
//
// Hypothesis under test (from VGPR_Count=32 in all rounds -> compiler sinks
// each gather to its use, ~2 outstanding/wave; 24 waves x 2 / ~350cyc L3
// = 0.137 req/cyc/CU = observed): the wall is outstanding-request
// starvation. Predict: VGPR 32 -> 70-90 (validity check), main combined
// 94 -> 45-70us, total -> 240-255us, absmax exactly 0.25. If VGPR rises
// but time flat: MLP falsified too -> L3 random-line throughput is the
// structural wall -> declare roofline.
//
// Retained (R11 best = 276.7us): fp16 full-cell pack P16[p][8] =
// {d0,d1}x{h0,h1}x{c0,c1} (clamp-baked, 16B/cell, 131MB ws), batch-split
// main (per-dispatch set 147MB < L3), 8 h-slice XCD regions, V=4 with
// k*BLK+tid mapping (adjacent lanes = adjacent voxels), scalar trf loads
// + sched_barrier fence, f32x2 nontemporal store, w-boundary folded into
// weights (exact). Fallback tiers: ws>=131MB -> R15; >=65.5MB -> R8; else f32.

#define BLK 256
constexpr int Bn = 2, Dn = 160, Hn = 160, Wn = 160;
constexpr int HQ = 40;                    // h-quarter rows (fallback paths)
constexpr int RSTRIP = HQ * Wn;           // 6400 voxels per (d, quarter) plane
constexpr int HQ2 = 20;                   // h-slice rows per XCD region (split)
constexpr int RSTRIP2 = HQ2 * Wn;         // 3200 voxels per (d, slice) plane
constexpr int V = 4;                      // voxels per thread

typedef float    f32x2  __attribute__((ext_vector_type(2)));
typedef float    f32x4  __attribute__((ext_vector_type(4), aligned(8)));   // vol reads (8B-safe)
typedef int      i32x4  __attribute__((ext_vector_type(4)));               // asm load payload (4 VGPRs)
typedef _Float16 h16x8  __attribute__((ext_vector_type(8), aligned(8)));   // 16B half-cell view
typedef _Float16 h16x16 __attribute__((ext_vector_type(16), aligned(16))); // cell pair at byte 16p

// ================= repack: vol f32 -> P16[p][8] = 8 cell corners ===========
// P16[p] = {d0h0c0,d0h0c1,d0h1c0,d0h1c1,d1h0c0,d1h0c1,d1h1c0,d1h1c1},
// d1/h1 clamp-baked. Each thread packs 2 consecutive-w voxels.
__global__ __launch_bounds__(BLK) void repack_dh(
    const float* __restrict__ vol, _Float16* __restrict__ pk)
{
    const int t  = blockIdx.x * BLK + threadIdx.x;   // 0 .. nvox/2-1
    const int v0 = t * 2;                            // even voxel id
    const int w  = v0 % Wn;                          // even (Wn%2==0)
    const int r  = v0 / Wn;                          // row id = (b*Dn+d)*Hn+h
    const int h  = r % Hn;
    const int d  = (r / Hn) % Dn;
    const int dh = (h < Hn - 1) ? 1 : 0;             // h-step (clamped)
    const int dd = (d < Dn - 1) ? Hn : 0;            // d-step in rows (clamped)

    const int r00 = r;                               // (d ,h )
    const int r01 = r + dh;                          // (d ,h1)
    const int r10 = r + dd;                          // (d1,h )
    const int r11 = r + dd + dh;                     // (d1,h1)

    const f32x4 A = *(const f32x4*)(vol + ((long long)(r00 * Wn + w) << 1));
    const f32x4 B = *(const f32x4*)(vol + ((long long)(r01 * Wn + w) << 1));
    const f32x4 C = *(const f32x4*)(vol + ((long long)(r10 * Wn + w) << 1));
    const f32x4 D = *(const f32x4*)(vol + ((long long)(r11 * Wn + w) << 1));

    h16x16 o;
    // voxel v0 (w):    x=c0, y=c1
    o[0]  = (_Float16)A.x; o[1]  = (_Float16)A.y;    // d0h0
    o[2]  = (_Float16)B.x; o[3]  = (_Float16)B.y;    // d0h1
    o[4]  = (_Float16)C.x; o[5]  = (_Float16)C.y;    // d1h0
    o[6]  = (_Float16)D.x; o[7]  = (_Float16)D.y;    // d1h1
    // voxel v0+1 (w+1): z=c0, w=c1
    o[8]  = (_Float16)A.z; o[9]  = (_Float16)A.w;
    o[10] = (_Float16)B.z; o[11] = (_Float16)B.w;
    o[12] = (_Float16)C.z; o[13] = (_Float16)C.w;
    o[14] = (_Float16)D.z; o[15] = (_Float16)D.w;
    *(h16x16*)(pk + ((long long)v0 << 3)) = o;       // 32B at byte 16*v0
}

// ================= R15 main: fused-asm gather batch, one batch/dispatch ====
__global__ __launch_bounds__(BLK, 4) void st_warp_kernel_mlp(
    const _Float16* __restrict__ pk,
    const float* __restrict__ trf,
    float* __restrict__ out,
    const int b)
{
    const int tid = threadIdx.x;
    const int sl  = blockIdx.x & 7;          // h-slice region (XCD heuristic)
    const int j   = blockIdx.x >> 3;         // 0..499 within region
    const int h0  = sl * HQ2;                // h-slice origin

    // ---- phase 0: voxel ids + ALL trf loads ----
    int   gvox[V], dk[V], hk[V], wk[V];
    float sd[V], sh[V], sw[V];
    #pragma unroll
    for (int k = 0; k < V; ++k) {
        const int v   = j * (BLK * V) + k * BLK + tid;   // region-linear voxel
        const int d   = v / RSTRIP2;
        const int rem = v - d * RSTRIP2;
        const int hh  = rem / Wn;
        const int w   = rem - hh * Wn;
        dk[k] = d; hk[k] = h0 + hh; wk[k] = w;
        gvox[k] = ((b * Dn + d) * Hn + (h0 + hh)) * Wn + w;
    }
    #pragma unroll
    for (int k = 0; k < V; ++k) {
        const float* tp = trf + (long long)gvox[k] * 3;
        sd[k] = __builtin_nontemporal_load(tp + 0);
        sh[k] = __builtin_nontemporal_load(tp + 1);
        sw[k] = __builtin_nontemporal_load(tp + 2);
    }
    __builtin_amdgcn_sched_barrier(0);   // keep all 12 trf loads issued here

    // ---- phase 1a: weights + gather addresses ----
    const _Float16* cp[V];
    float wA[V], wB[V], wC[V], wD[V], w0k[V], w1k[V];
    #pragma unroll
    for (int k = 0; k < V; ++k) {
        float loc, c0f, c1f;

        loc = (float)dk[k] + sd[k];
        c0f = fminf(fmaxf(floorf(loc), 0.0f), (float)(Dn - 1));
        c1f = fminf(c0f + 1.0f, (float)(Dn - 1));
        const float wd0 = c1f - loc, wd1 = 1.0f - wd0;
        const int id0 = (int)c0f;                 // id1 baked into packed data

        loc = (float)hk[k] + sh[k];
        c0f = fminf(fmaxf(floorf(loc), 0.0f), (float)(Hn - 1));
        c1f = fminf(c0f + 1.0f, (float)(Hn - 1));
        const float wh0 = c1f - loc, wh1 = 1.0f - wh0;
        const int ih0 = (int)c0f;                 // ih1 baked into packed data

        loc = (float)wk[k] + sw[k];
        c0f = fminf(fmaxf(floorf(loc), 0.0f), (float)(Wn - 1));
        c1f = fminf(c0f + 1.0f, (float)(Wn - 1));
        const float ww0 = c1f - loc, ww1 = 1.0f - ww0;
        const int iw0 = (int)c0f;

        const bool lo = (iw0 < Wn - 1);
        const int  m  = lo ? iw0 : (Wn - 2);
        // boundary: corner0 weight -> 0, corner1 weight -> 1 (exact: ww0+ww1==1)
        w0k[k] = lo ? ww0 : 0.0f;
        w1k[k] = lo ? ww1 : 1.0f;
        wA[k] = wd0 * wh0; wB[k] = wd0 * wh1;
        wC[k] = wd1 * wh0; wD[k] = wd1 * wh1;

        const long long p0 = ((b * Dn + id0) * Hn + ih0) * Wn + m;  // w-pair base
        cp[k] = pk + (p0 << 3);                    // 32B cell pair (16B-aligned)
    }

    // ---- phase 1b: ONE asm block: 8 loads back-to-back + hardware wait ----
    // Outputs are defined only at block end (after s_waitcnt) -> the
    // compiler cannot touch them earlier; "=&v" keeps them disjoint from
    // the address pairs while 8 loads are in flight.
    i32x4 g0, g1, g2, g3, g4, g5, g6, g7;
    asm volatile(
        "global_load_dwordx4 %0, %8, off\n\t"
        "global_load_dwordx4 %1, %8, off offset:16\n\t"
        "global_load_dwordx4 %2, %9, off\n\t"
        "global_load_dwordx4 %3, %9, off offset:16\n\t"
        "global_load_dwordx4 %4, %10, off\n\t"
        "global_load_dwordx4 %5, %10, off offset:16\n\t"
        "global_load_dwordx4 %6, %11, off\n\t"
        "global_load_dwordx4 %7, %11, off offset:16\n\t"
        "s_waitcnt vmcnt(0)"
        : "=&v"(g0), "=&v"(g1), "=&v"(g2), "=&v"(g3),
          "=&v"(g4), "=&v"(g5), "=&v"(g6), "=&v"(g7)
        : "v"(cp[0]), "v"(cp[1]), "v"(cp[2]), "v"(cp[3]));

    // ---- phase 2: convert + combine + store ----
    i32x4 glo[V] = { g0, g2, g4, g6 };
    i32x4 ghi[V] = { g1, g3, g5, g7 };
    #pragma unroll
    for (int k = 0; k < V; ++k) {
        const h16x8 a  = __builtin_bit_cast(h16x8, glo[k]);  // w-corner0 cell
        const h16x8 c  = __builtin_bit_cast(h16x8, ghi[k]);  // w-corner1 cell
        // cell layout: [i] with i = d*4 + h*2 + ch
        const float acc0 =
              wA[k] * (w0k[k] * (float)a[0] + w1k[k] * (float)c[0])
            + wB[k] * (w0k[k] * (float)a[2] + w1k[k] * (float)c[2])
            + wC[k] * (w0k[k] * (float)a[4] + w1k[k] * (float)c[4])
            + wD[k] * (w0k[k] * (float)a[6] + w1k[k] * (float)c[6]);
        const float acc1 =
              wA[k] * (w0k[k] * (float)a[1] + w1k[k] * (float)c[1])
            + wB[k] * (w0k[k] * (float)a[3] + w1k[k] * (float)c[3])
            + wC[k] * (w0k[k] * (float)a[5] + w1k[k] * (float)c[5])
            + wD[k] * (w0k[k] * (float)a[7] + w1k[k] * (float)c[7]);
        f32x2 res; res.x = acc0; res.y = acc1;
        __builtin_nontemporal_store(res, &((f32x2*)out)[gvox[k]]);
    }
}

// ================= R8 tier: h-pair pack (known-good middle fallback) =======
__global__ __launch_bounds__(BLK) void repack_h_pairs(
    const float* __restrict__ vol, _Float16* __restrict__ pk)
{
    const int t  = blockIdx.x * BLK + threadIdx.x;   // 0 .. 4,095,999
    const int v0 = t * 2;                            // even voxel id
    const int w  = v0 % Wn;                          // even (Wn%2==0)
    const int r  = v0 / Wn;                          // row id = (b*Dn+d)*Hn+h
    const int h  = r % Hn;
    const int hc = (h < Hn - 1) ? (h + 1) : h;       // clamped h+1
    const int r1 = r - h + hc;                       // row id at hc

    const f32x4 a = *(const f32x4*)(vol + ((long long)v0 << 1));
    const f32x4 b = *(const f32x4*)(vol + ((long long)(r1 * Wn + w) << 1));

    h16x8 o;
    o[0] = (_Float16)a.x; o[1] = (_Float16)a.y;
    o[2] = (_Float16)b.x; o[3] = (_Float16)b.y;
    o[4] = (_Float16)a.z; o[5] = (_Float16)a.w;
    o[6] = (_Float16)b.z; o[7] = (_Float16)b.w;
    *(h16x8*)(pk + ((long long)v0 << 2)) = o;
}

__global__ __launch_bounds__(BLK, 4) void st_warp_kernel_pk(
    const _Float16* __restrict__ pk,
    const float* __restrict__ trf,
    float* __restrict__ out)
{
    const int tid = threadIdx.x;
    const int xcd = blockIdx.x & 7;
    const int j   = blockIdx.x >> 3;
    const int b   = xcd >> 2;
    const int h0  = (xcd & 3) * HQ;

    int   gvox[V];
    float sd[V], sh[V], sw[V];
    #pragma unroll
    for (int k = 0; k < V; ++k) {
        const int v   = j * (BLK * V) + k * BLK + tid;
        const int d   = v / RSTRIP;
        const int rem = v - d * RSTRIP;
        const int hh  = rem / Wn;
        const int w   = rem - hh * Wn;
        gvox[k] = ((b * Dn + d) * Hn + (h0 + hh)) * Wn + w;
    }
    #pragma unroll
    for (int k = 0; k < V; ++k) {
        const float* tp = trf + (long long)gvox[k] * 3;
        sd[k] = __builtin_nontemporal_load(tp + 0);
        sh[k] = __builtin_nontemporal_load(tp + 1);
        sw[k] = __builtin_nontemporal_load(tp + 2);
    }

    h16x8 val[2 * V];
    float wA[V], wB[V], wC[V], wD[V], w0[V], w1[V];
    #pragma unroll
    for (int k = 0; k < V; ++k) {
        const int v   = j * (BLK * V) + k * BLK + tid;
        const int d   = v / RSTRIP;
        const int rem = v - d * RSTRIP;
        const int hh  = rem / Wn;
        const int w   = rem - hh * Wn;
        const int h   = h0 + hh;

        float loc, c0f, c1f;

        loc = (float)d + sd[k];
        c0f = fminf(fmaxf(floorf(loc), 0.0f), (float)(Dn - 1));
        c1f = fminf(c0f + 1.0f, (float)(Dn - 1));
        const float wd0 = c1f - loc, wd1 = 1.0f - wd0;
        const int id0 = (int)c0f, id1 = (int)c1f;

        loc = (float)h + sh[k];
        c0f = fminf(fmaxf(floorf(loc), 0.0f), (float)(Hn - 1));
        c1f = fminf(c0f + 1.0f, (float)(Hn - 1));
        const float wh0 = c1f - loc, wh1 = 1.0f - wh0;
        const int ih0 = (int)c0f;

        loc = (float)w + sw[k];
        c0f = fminf(fmaxf(floorf(loc), 0.0f), (float)(Wn - 1));
        c1f = fminf(c0f + 1.0f, (float)(Wn - 1));
        const float ww0 = c1f - loc, ww1 = 1.0f - ww0;
        const int iw0 = (int)c0f;

        const bool lo = (iw0 < Wn - 1);
        const int  m  = lo ? iw0 : (Wn - 2);
        w0[k] = lo ? ww0 : 0.0f;
        w1[k] = lo ? ww1 : 1.0f;
        wA[k] = wd0 * wh0; wB[k] = wd0 * wh1;
        wC[k] = wd1 * wh0; wD[k] = wd1 * wh1;

        const int bo = b * Dn;
        const int p0 = ((bo + id0) * Hn + ih0) * Wn + m;
        const int p1 = ((bo + id1) * Hn + ih0) * Wn + m;

        val[2 * k + 0] = *(const h16x8*)(pk + ((long long)p0 << 2));
        val[2 * k + 1] = *(const h16x8*)(pk + ((long long)p1 << 2));
    }

    #pragma unroll
    for (int k = 0; k < V; ++k) {
        const h16x8 a = val[2 * k + 0];
        const h16x8 c = val[2 * k + 1];
        const float acc0 =
              wA[k] * (w0[k] * (float)a[0] + w1[k] * (float)a[4])
            + wB[k] * (w0[k] * (float)a[2] + w1[k] * (float)a[6])
            + wC[k] * (w0[k] * (float)c[0] + w1[k] * (float)c[4])
            + wD[k] * (w0[k] * (float)c[2] + w1[k] * (float)c[6]);
        const float acc1 =
              wA[k] * (w0[k] * (float)a[1] + w1[k] * (float)a[5])
            + wB[k] * (w0[k] * (float)a[3] + w1[k] * (float)a[7])
            + wC[k] * (w0[k] * (float)c[1] + w1[k] * (float)c[5])
            + wD[k] * (w0[k] * (float)c[3] + w1[k] * (float)c[7]);
        f32x2 res; res.x = acc0; res.y = acc1;
        __builtin_nontemporal_store(res, &((f32x2*)out)[gvox[k]]);
    }
}

// ================= R5 tier: f32 direct (last-resort fallback) ==============
__global__ __launch_bounds__(BLK, 4) void st_warp_kernel_f32(
    const float* __restrict__ vol,
    const float* __restrict__ trf,
    float* __restrict__ out)
{
    const int tid = threadIdx.x;
    const int xcd = blockIdx.x & 7;
    const int j   = blockIdx.x >> 3;
    const int b   = xcd >> 2;
    const int h0  = (xcd & 3) * HQ;

    int   gvox[V];
    float sd[V], sh[V], sw[V];
    #pragma unroll
    for (int k = 0; k < V; ++k) {
        const int v   = j * (BLK * V) + k * BLK + tid;
        const int d   = v / RSTRIP;
        const int rem = v - d * RSTRIP;
        const int hh  = rem / Wn;
        const int w   = rem - hh * Wn;
        gvox[k] = ((b * Dn + d) * Hn + (h0 + hh)) * Wn + w;
    }
    #pragma unroll
    for (int k = 0; k < V; ++k) {
        const float* tp = trf + (long long)gvox[k] * 3;
        sd[k] = __builtin_nontemporal_load(tp + 0);
        sh[k] = __builtin_nontemporal_load(tp + 1);
        sw[k] = __builtin_nontemporal_load(tp + 2);
    }

    f32x4 val[4 * V];
    float wA[V], wB[V], wC[V], wD[V], w0[V], w1[V];
    #pragma unroll
    for (int k = 0; k < V; ++k) {
        const int v   = j * (BLK * V) + k * BLK + tid;
        const int d   = v / RSTRIP;
        const int rem = v - d * RSTRIP;
        const int hh  = rem / Wn;
        const int w   = rem - hh * Wn;
        const int h   = h0 + hh;

        float loc, c0f, c1f;

        loc = (float)d + sd[k];
        c0f = fminf(fmaxf(floorf(loc), 0.0f), (float)(Dn - 1));
        c1f = fminf(c0f + 1.0f, (float)(Dn - 1));
        const float wd0 = c1f - loc, wd1 = 1.0f - wd0;
        const int id0 = (int)c0f, id1 = (int)c1f;

        loc = (float)h + sh[k];
        c0f = fminf(fmaxf(floorf(loc), 0.0f), (float)(Hn - 1));
        c1f = fminf(c0f + 1.0f, (float)(Hn - 1));
        const float wh0 = c1f - loc, wh1 = 1.0f - wh0;
        const int ih0 = (int)c0f, ih1 = (int)c1f;

        loc = (float)w + sw[k];
        c0f = fminf(fmaxf(floorf(loc), 0.0f), (float)(Wn - 1));
        c1f = fminf(c0f + 1.0f, (float)(Wn - 1));
        const float ww0 = c1f - loc, ww1 = 1.0f - ww0;
        const int iw0 = (int)c0f;

        const bool lo = (iw0 < Wn - 1);
        const int  m  = lo ? iw0 : (Wn - 2);
        w0[k] = lo ? ww0 : 0.0f;
        w1[k] = lo ? ww1 : 1.0f;
        wA[k] = wd0 * wh0; wB[k] = wd0 * wh1;
        wC[k] = wd1 * wh0; wD[k] = wd1 * wh1;

        const int bo  = b * Dn;
        const int r00 = ((bo + id0) * Hn + ih0) * Wn;
        const int r01 = ((bo + id0) * Hn + ih1) * Wn;
        const int r10 = ((bo + id1) * Hn + ih0) * Wn;
        const int r11 = ((bo + id1) * Hn + ih1) * Wn;

        val[4 * k + 0] = *(const f32x4*)(vol + (((long long)(r00 + m)) << 1));
        val[4 * k + 1] = *(const f32x4*)(vol + (((long long)(r01 + m)) << 1));
        val[4 * k + 2] = *(const f32x4*)(vol + (((long long)(r10 + m)) << 1));
        val[4 * k + 3] = *(const f32x4*)(vol + (((long long)(r11 + m)) << 1));
    }

    #pragma unroll
    for (int k = 0; k < V; ++k) {
        const f32x4 vA = val[4 * k + 0], vB = val[4 * k + 1];
        const f32x4 vC = val[4 * k + 2], vD = val[4 * k + 3];
        const float acc0 = wA[k] * (w0[k] * vA.x + w1[k] * vA.z)
                         + wB[k] * (w0[k] * vB.x + w1[k] * vB.z)
                         + wC[k] * (w0[k] * vC.x + w1[k] * vC.z)
                         + wD[k] * (w0[k] * vD.x + w1[k] * vD.z);
        const float acc1 = wA[k] * (w0[k] * vA.y + w1[k] * vA.w)
                         + wB[k] * (w0[k] * vB.y + w1[k] * vB.w)
                         + wC[k] * (w0[k] * vC.y + w1[k] * vC.w)
                         + wD[k] * (w0[k] * vD.y + w1[k] * vD.w);
        f32x2 res; res.x = acc0; res.y = acc1;
        __builtin_nontemporal_store(res, &((f32x2*)out)[gvox[k]]);
    }
}

extern "C" void kernel_launch(void* const* d_in, const int* in_sizes, int n_in,
                              void* d_out, int out_size, void* d_ws, size_t ws_size,
                              hipStream_t stream) {
    const float* vol = (const float*)d_in[0];
    const float* trf = (const float*)d_in[1];
    float* out = (float*)d_out;

    const int nvox = Bn * Dn * Hn * Wn;               // 8,192,000
    const size_t pk16_bytes = (size_t)nvox * 8 * sizeof(_Float16);  // 131,072,000
    const size_t pk8_bytes  = (size_t)nvox * 4 * sizeof(_Float16);  //  65,536,000
    const int rgrid = (nvox / 2) / BLK;               // 16000 blocks

    if (d_ws != nullptr && ws_size >= pk16_bytes) {
        _Float16* pk = (_Float16*)d_ws;
        const int hgrid = (nvox / 2) / (BLK * V);     // 4000 blocks/batch, %8==0
        repack_dh<<<rgrid, BLK, 0, stream>>>(vol, pk);
        st_warp_kernel_mlp<<<hgrid, BLK, 0, stream>>>(pk, trf, out, 0);
        st_warp_kernel_mlp<<<hgrid, BLK, 0, stream>>>(pk, trf, out, 1);
    } else if (d_ws != nullptr && ws_size >= pk8_bytes) {
        _Float16* pk = (_Float16*)d_ws;
        const int grid = nvox / (BLK * V);            // 8000 blocks
        repack_h_pairs<<<rgrid, BLK, 0, stream>>>(vol, pk);
        st_warp_kernel_pk<<<grid, BLK, 0, stream>>>(pk, trf, out);
    } else {
        const int grid = nvox / (BLK * V);
        st_warp_kernel_f32<<<grid, BLK, 0, stream>>>(vol, trf, out);
    }
}